// Round 3
// baseline (11856.461 us; speedup 1.0000x reference)
//
#include <hip/hip_runtime.h>

// ---------------------------------------------------------------------------
// 3-layer SimpleRNN, B=256 T=512 U=512 E=128, fp16 MFMA.
// R3: one 1024-thread block per (layer, 16-row batch group) -> 48 blocks.
// The per-layer recurrence cycle is entirely LDS-local (zero global hops);
// only the feed-forward cross-layer edge goes through a global ring buffer
// with deferred-published sc flags (single-writer store, all-lane load poll,
// no atomics, no drains on the critical path).
// ---------------------------------------------------------------------------

#define BATCH 256
#define SEQ   512
#define EMBD  128
#define UNIT  512

typedef _Float16 half8 __attribute__((ext_vector_type(8)));
typedef _Float16 half4 __attribute__((ext_vector_type(4)));
typedef float    f32x4 __attribute__((ext_vector_type(4)));
typedef unsigned int uint4v __attribute__((ext_vector_type(4)));

// ws layout (bytes). Total ~4.1 MB (< 4.63 MB proven in R1/R2).
// hbuf tiles: 16KB each (16 rows x 512 cols f16). Layers 0,1: 16 groups x 4
// ring slots (tiles 0..127). Layer 2: 16 groups x 1 slot (tiles 128..143).
#define FLAGS_BYTES 8192
#define HBUF_OFF    8192
#define TILE_ELEMS  (16*512)
#define N_TILES     (2*16*4 + 16)
#define HBUF_BYTES  (N_TILES*TILE_ELEMS*2)
#define PWX0_OFF    (HBUF_OFF + HBUF_BYTES)
#define PWH0_OFF    (PWX0_OFF + EMBD*UNIT*2)
#define PWX1_OFF    (PWH0_OFF + UNIT*UNIT*2)
#define PWH1_OFF    (PWX1_OFF + UNIT*UNIT*2)

// ---------------------------------------------------------------------------
__device__ __forceinline__ int sc_ld_int(const int* p) {
    int r;
    asm volatile("global_load_dword %0, %1, off sc0 sc1\n\ts_waitcnt vmcnt(0)"
                 : "=v"(r) : "v"(p) : "memory");
    return r;
}
__device__ __forceinline__ void sc_st_int(int* p, int v) {
    asm volatile("global_store_dword %0, %1, off sc0 sc1" :: "v"(p), "v"(v) : "memory");
}
__device__ __forceinline__ void sc_load_issue(const uint4v* p, uint4v& r) {
    asm volatile("global_load_dwordx4 %0, %1, off sc0 sc1" : "=v"(r) : "v"(p) : "memory");
}
__device__ __forceinline__ void vm_wait_tied(uint4v& a) {
    asm volatile("s_waitcnt vmcnt(0)" : "+v"(a) :: "memory");
}
__device__ __forceinline__ void sc_store16(uint4v* p, uint4v v) {
    asm volatile("global_store_dwordx4 %0, %1, off sc0 sc1" :: "v"(p), "v"(v) : "memory");
}

// ---------------------------------------------------------------------------
__global__ void zero_ws_kernel(uint4v* __restrict__ p, int n16) {
    int i = blockIdx.x * 256 + threadIdx.x;
    uint4v z = {0u, 0u, 0u, 0u};
    if (i < n16) p[i] = z;
}

// Pack fp32 weight [K][N] into MFMA B-fragment order, fp16:
// dst[((nt*KT + kt)*64 + lane)*8 + j] = W[kt*32 + (lane>>4)*8 + j][nt*16 + (lane&15)]
__global__ void pack_w_kernel(const float* __restrict__ src, _Float16* __restrict__ dst,
                              int K, int N) {
    int idx = blockIdx.x * 256 + threadIdx.x;
    if (idx >= K * N) return;
    int j    = idx & 7;
    int lane = (idx >> 3) & 63;
    int rest = idx >> 9;
    int KT   = K >> 5;
    int kt   = rest % KT;
    int nt   = rest / KT;
    int k = kt*32 + (lane >> 4)*8 + j;
    int n = nt*16 + (lane & 15);
    dst[idx] = (_Float16)src[k * N + n];
}

// ---------------------------------------------------------------------------
__global__ __launch_bounds__(1024, 4)
void rnn_main_kernel(const int*   __restrict__ tokens,
                     const float* __restrict__ emb,
                     const float* __restrict__ b0,
                     const float* __restrict__ b1,
                     char* ws)
{
    const int bid   = blockIdx.x;
    const int layer = bid >> 4;          // 0..2
    const int mg    = bid & 15;          // batch group (16 rows)
    const int tid   = threadIdx.x;       // 0..1023, 16 waves
    const int wv    = tid >> 6;
    const int lane  = tid & 63;
    const int q     = lane >> 4;
    const int c16   = lane & 15;

    int* flags = (int*)ws;               // stride 32 ints = 128B per flag
    int* fOwn  = flags + (layer*16 + mg)*32;
    int* fUp   = flags + ((layer-1)*16 + mg)*32;
    int* fDn   = flags + ((layer+1)*16 + mg)*32;

    _Float16* hbuf = (_Float16*)(ws + HBUF_OFF);
    const _Float16* pWh = (const _Float16*)(ws + (layer == 0 ? PWH0_OFF : PWH1_OFF));
    const _Float16* pWx = (const _Float16*)(ws + (layer == 0 ? PWX0_OFF : PWX1_OFF));
    const float* bias = (layer == 0) ? b0 : b1;

    const int c0  = wv*32;               // col base of this wave
    const int nt0 = wv*2;

    // LDS: 82.25 KB total. Rows swizzled by 16B-chunk rotation ((chunk+row)&63).
    __shared__ _Float16 Ah [16][512];    // h_l(t-1): the recurrence state
    __shared__ _Float16 Ain[16][512];    // input A-tile (x_t or h_{l-1}(t))
    __shared__ _Float16 Bounce[16][520]; // epilogue coalescing (row pad 16B)
    __shared__ int      Tok[16*512];     // tokens for this batch group (l0)

    // zero Ah: h(-1) = 0  (1024 16B chunks)
    { uint4v z = {0u,0u,0u,0u}; ((uint4v*)Ah)[tid] = z; }
    // token preload (l0): 8192 ints = 2048 int4
    if (layer == 0) {
        const int4* src = (const int4*)(tokens + mg*16*SEQ);
        int4* d = (int4*)Tok;
        d[tid] = src[tid];
        d[1024 + tid] = src[1024 + tid];
    }

    // ---- register-resident weights (B-fragments): wave owns 32 cols ----
    half8 whf[16][2];
    half8 wxf[16][2];
#pragma unroll
    for (int kt = 0; kt < 16; ++kt)
#pragma unroll
        for (int n = 0; n < 2; ++n)
            whf[kt][n] = *(const half8*)&pWh[(((nt0 + n)*16 + kt)*64 + lane) * 8];
    if (layer == 0) {
#pragma unroll
        for (int kt = 0; kt < 4; ++kt)
#pragma unroll
            for (int n = 0; n < 2; ++n)
                wxf[kt][n] = *(const half8*)&pWx[(((nt0 + n)*4 + kt)*64 + lane) * 8];
    } else {
#pragma unroll
        for (int kt = 0; kt < 16; ++kt)
#pragma unroll
            for (int n = 0; n < 2; ++n)
                wxf[kt][n] = *(const half8*)&pWx[(((nt0 + n)*16 + kt)*64 + lane) * 8];
    }

    const float bv0 = bias[c0 + c16];
    const float bv1 = bias[c0 + 16 + c16];
    __syncthreads();

    const int r64 = tid >> 6;            // chunk row for 1024-chunk tile ops
    const int cc64 = tid & 63;           // chunk col

    for (int t = 0; t < SEQ; ++t) {
        // drain our step-(t-1) ring stores (wave-wide); makes the deferred
        // flag publish at the END of this step valid for steps <= t-1.
        asm volatile("s_waitcnt vmcnt(0)" ::: "memory");

        // polls: all lanes (coalesced single request/wave, no RMW, no barrier)
        if (layer > 0) {
            while (sc_ld_int(fUp) < t + 1) __builtin_amdgcn_s_sleep(2);
        }
        if (layer < 2 && t >= 4) {
            while (sc_ld_int(fDn) < t - 3) __builtin_amdgcn_s_sleep(2);
        }

        // issue in-feed load early (hidden under Wh GEMM)
        uint4v inChunk;
        if (layer > 0) {
            const uint4v* sb = (const uint4v*)
                (hbuf + (((layer-1)*16 + mg)*4 + (t & 3)) * TILE_ELEMS);
            sc_load_issue(sb + tid, inChunk);
        }
        // issue embedding gather early (compiler sinks the waitcnt to use)
        float4 g;
        int gr = 0, gq = 0;
        if (layer == 0 && tid < 512) {
            gr = tid >> 5; gq = tid & 31;
            int tok = Tok[gr*512 + t];
            g = ((const float4*)emb)[tok*32 + gq];
        }

        f32x4 acc0 = {0,0,0,0}, acc1 = {0,0,0,0};

        // ---- Wh GEMM: h_l(t-1) @ Wh[:, wave cols]  (LDS-local recurrence) ----
#pragma unroll
        for (int kt = 0; kt < 16; ++kt) {
            half8 a = *(const half8*)&Ah[c16][((kt*4 + q + c16) & 63) * 8];
            acc0 = __builtin_amdgcn_mfma_f32_16x16x32_f16(a, whf[kt][0], acc0, 0, 0, 0);
            acc1 = __builtin_amdgcn_mfma_f32_16x16x32_f16(a, whf[kt][1], acc1, 0, 0, 0);
        }

        // ---- stage input tile -> Ain ----
        if (layer > 0) {
            vm_wait_tied(inChunk);
            *(uint4v*)&Ain[r64][((cc64 + r64) & 63) * 8] = inChunk;
        } else if (tid < 512) {
            half4 h = { (_Float16)g.x, (_Float16)g.y, (_Float16)g.z, (_Float16)g.w };
            *(half4*)&Ain[gr][((((gq >> 1) + gr) & 63) * 8) + (gq & 1) * 4] = h;
        }
        __syncthreads();   // (B) Ain ready

        // ---- Wx GEMM ----
        if (layer == 0) {
#pragma unroll
            for (int kt = 0; kt < 4; ++kt) {
                half8 a = *(const half8*)&Ain[c16][((kt*4 + q + c16) & 63) * 8];
                acc0 = __builtin_amdgcn_mfma_f32_16x16x32_f16(a, wxf[kt][0], acc0, 0, 0, 0);
                acc1 = __builtin_amdgcn_mfma_f32_16x16x32_f16(a, wxf[kt][1], acc1, 0, 0, 0);
            }
        } else {
#pragma unroll
            for (int kt = 0; kt < 16; ++kt) {
                half8 a = *(const half8*)&Ain[c16][((kt*4 + q + c16) & 63) * 8];
                acc0 = __builtin_amdgcn_mfma_f32_16x16x32_f16(a, wxf[kt][0], acc0, 0, 0, 0);
                acc1 = __builtin_amdgcn_mfma_f32_16x16x32_f16(a, wxf[kt][1], acc1, 0, 0, 0);
            }
        }

        // ---- epilogue: +bias, tanh -> Bounce ----
#pragma unroll
        for (int r = 0; r < 4; ++r) {
            int row = q*4 + r;
            float z, e;
            z = acc0[r] + bv0; e = __expf(2.0f*z);
            Bounce[row][c0 + c16]      = (_Float16)(1.0f - 2.0f/(e + 1.0f));
            z = acc1[r] + bv1; e = __expf(2.0f*z);
            Bounce[row][c0 + 16 + c16] = (_Float16)(1.0f - 2.0f/(e + 1.0f));
        }
        __syncthreads();   // (E) Bounce ready; all Ah/Ain reads done

        // ---- Bounce -> Ah(t) (LDS recurrence) + ring store (fire-and-forget) ----
        {
            uint4v v = *(const uint4v*)&Bounce[r64][cc64 * 8];
            *(uint4v*)&Ah[r64][((cc64 + r64) & 63) * 8] = v;
            if (layer < 2) {
                _Float16* tc = hbuf + ((layer*16 + mg)*4 + (t & 3)) * TILE_ELEMS;
                sc_store16((uint4v*)tc + tid, v);
            } else if (t == SEQ - 1) {
                _Float16* tc = hbuf + (128 + mg) * TILE_ELEMS;
                sc_store16((uint4v*)tc + tid, v);
            }
        }
        __syncthreads();   // (F) Ah(t) complete; safe for next step's Wh
        // deferred publish: flag = t  <=>  "steps <= t-1 drained at L3"
        if (tid == 0) sc_st_int(fOwn, t);
    }

    // final publish so consumers can reach t=511 (h(511) drained here)
    asm volatile("s_waitcnt vmcnt(0)" ::: "memory");
    __syncthreads();
    if (tid == 0) sc_st_int(fOwn, SEQ);
}

// ---------------------------------------------------------------------------
// logits = h2(T-1) @ fc_w + fc_b ; out = sigmoid(logits). One wave per row.
__global__ void fc_kernel(const char* __restrict__ ws,
                          const float* __restrict__ fc_w,
                          const float* __restrict__ fc_b,
                          float* __restrict__ out)
{
    int row  = blockIdx.x;
    int lane = threadIdx.x;          // 64
    int m = row >> 4, lr = row & 15;
    const _Float16* h2 = (const _Float16*)(ws + HBUF_OFF)
                         + (128 + m) * TILE_ELEMS + lr * UNIT;
    half8 hv = *(const half8*)&h2[lane * 8];
    const float* w = fc_w + lane * 8;
    float s = 0.0f;
#pragma unroll
    for (int j = 0; j < 8; ++j) s += (float)hv[j] * w[j];
#pragma unroll
    for (int off = 32; off > 0; off >>= 1) s += __shfl_down(s, off);
    if (lane == 0) {
        float logit = s + fc_b[0];
        out[row] = 1.0f / (1.0f + __expf(-logit));
    }
}

// ---------------------------------------------------------------------------
extern "C" void kernel_launch(void* const* d_in, const int* in_sizes, int n_in,
                              void* d_out, int out_size, void* d_ws, size_t ws_size,
                              hipStream_t stream)
{
    const int*   tokens = (const int*)  d_in[0];
    const float* emb    = (const float*)d_in[1];
    const float* Wx0    = (const float*)d_in[2];
    const float* Wh0    = (const float*)d_in[3];
    const float* b0     = (const float*)d_in[4];
    const float* Wx1    = (const float*)d_in[5];
    const float* Wh1    = (const float*)d_in[6];
    const float* b1     = (const float*)d_in[7];
    const float* fcw    = (const float*)d_in[8];
    const float* fcb    = (const float*)d_in[9];
    char*  ws  = (char*)d_ws;
    float* out = (float*)d_out;

    // 1) zero flags (ring tiles are never read before being written)
    int n16 = FLAGS_BYTES / 16;
    zero_ws_kernel<<<(n16 + 255)/256, 256, 0, stream>>>((uint4v*)ws, n16);

    // 2) pack weights fp32 -> fp16 B-fragment layout
    pack_w_kernel<<<(EMBD*UNIT + 255)/256, 256, 0, stream>>>(Wx0, (_Float16*)(ws + PWX0_OFF), EMBD, UNIT);
    pack_w_kernel<<<(UNIT*UNIT + 255)/256, 256, 0, stream>>>(Wh0, (_Float16*)(ws + PWH0_OFF), UNIT, UNIT);
    pack_w_kernel<<<(UNIT*UNIT + 255)/256, 256, 0, stream>>>(Wx1, (_Float16*)(ws + PWX1_OFF), UNIT, UNIT);
    pack_w_kernel<<<(UNIT*UNIT + 255)/256, 256, 0, stream>>>(Wh1, (_Float16*)(ws + PWH1_OFF), UNIT, UNIT);

    // 3) pipelined recurrence: 48 blocks = 3 layers x 16 batch groups, 1024 thr
    rnn_main_kernel<<<48, 1024, 0, stream>>>(tokens, emb, b0, b1, ws);

    // 4) final FC + sigmoid
    fc_kernel<<<256, 64, 0, stream>>>((const char*)ws, fcw, fcb, out);
}

// Round 5
// 2631.886 us; speedup vs baseline: 4.5049x; 4.5049x over previous
//
#include <hip/hip_runtime.h>

// ---------------------------------------------------------------------------
// 3-layer SimpleRNN, B=256 T=512 U=512 E=128, fp16 MFMA.
// R5: 96 blocks = 3 layers x 8 batch-groups x 4 N-strips, 256 thr,
// register-resident weights (1 wave/SIMD).
//  - polls: plain sc0sc1 loads, one 3-quad round trip, tid0 only (no RMW)
//  - publish: single-writer sc0sc1 store after per-lane store drain
//  - h exchange: ONE combined 14-load asm block (6 sibling-Ah + 8 Ain chunks)
//    with in-block vmcnt(0)  [sound: no in-flight VGPRs visible to regalloc]
//  - hbuf zeroed (t=0 reads ring slot 3); ALL layers store ring every step
// ---------------------------------------------------------------------------

#define BATCH 256
#define SEQ   512
#define EMBD  128
#define UNIT  512

typedef _Float16 half8 __attribute__((ext_vector_type(8)));
typedef _Float16 half4 __attribute__((ext_vector_type(4)));
typedef float    f32x4 __attribute__((ext_vector_type(4)));
typedef unsigned int uint4v __attribute__((ext_vector_type(4)));
typedef int      int4v __attribute__((ext_vector_type(4)));

// ws layout (bytes). Total ~4.63 MB.
#define FLAGS_BYTES 4096
#define HBUF_OFF    4096
#define HBUF_ELEMS  (3*8*4*32*512)          // [layer][mgroup][slot][32][512] f16
#define HBUF_BYTES  (HBUF_ELEMS*2)
#define PWX0_OFF    (HBUF_OFF + HBUF_BYTES)
#define PWH0_OFF    (PWX0_OFF + EMBD*UNIT*2)
#define PWX1_OFF    (PWH0_OFF + UNIT*UNIT*2)
#define PWH1_OFF    (PWX1_OFF + UNIT*UNIT*2)

// ---------------------------------------------------------------------------
__device__ __forceinline__ void sc_st_int(int* p, int v) {
    asm volatile("global_store_dword %0, %1, off sc0 sc1" :: "v"(p), "v"(v) : "memory");
}

// three flag quads in one round trip (combined issue+wait: sound)
__device__ __forceinline__ void sc_ld_q3(const int* p0, const int* p1, const int* p2,
                                         int4v& a, int4v& b, int4v& c) {
    asm volatile(
        "global_load_dwordx4 %0, %3, off sc0 sc1\n\t"
        "global_load_dwordx4 %1, %4, off sc0 sc1\n\t"
        "global_load_dwordx4 %2, %5, off sc0 sc1\n\t"
        "s_waitcnt vmcnt(0)"
        : "=&v"(a), "=&v"(b), "=&v"(c)
        : "v"(p0), "v"(p1), "v"(p2)
        : "memory");
}

// 14 loads (6 Ah + 8 Ain) + single wait, one round trip, one asm block
__device__ __forceinline__ void sc_load14(
    const uint4v* a0, const uint4v* a1, const uint4v* a2,
    const uint4v* a3, const uint4v* a4, const uint4v* a5,
    const uint4v* b0, const uint4v* b1, const uint4v* b2, const uint4v* b3,
    const uint4v* b4, const uint4v* b5, const uint4v* b6, const uint4v* b7,
    uint4v& s0, uint4v& s1, uint4v& s2, uint4v& s3, uint4v& s4, uint4v& s5,
    uint4v& r0, uint4v& r1, uint4v& r2, uint4v& r3,
    uint4v& r4, uint4v& r5, uint4v& r6, uint4v& r7)
{
    asm volatile(
        "global_load_dwordx4 %0, %14, off sc0 sc1\n\t"
        "global_load_dwordx4 %1, %15, off sc0 sc1\n\t"
        "global_load_dwordx4 %2, %16, off sc0 sc1\n\t"
        "global_load_dwordx4 %3, %17, off sc0 sc1\n\t"
        "global_load_dwordx4 %4, %18, off sc0 sc1\n\t"
        "global_load_dwordx4 %5, %19, off sc0 sc1\n\t"
        "global_load_dwordx4 %6, %20, off sc0 sc1\n\t"
        "global_load_dwordx4 %7, %21, off sc0 sc1\n\t"
        "global_load_dwordx4 %8, %22, off sc0 sc1\n\t"
        "global_load_dwordx4 %9, %23, off sc0 sc1\n\t"
        "global_load_dwordx4 %10, %24, off sc0 sc1\n\t"
        "global_load_dwordx4 %11, %25, off sc0 sc1\n\t"
        "global_load_dwordx4 %12, %26, off sc0 sc1\n\t"
        "global_load_dwordx4 %13, %27, off sc0 sc1\n\t"
        "s_waitcnt vmcnt(0)"
        : "=&v"(s0), "=&v"(s1), "=&v"(s2), "=&v"(s3), "=&v"(s4), "=&v"(s5),
          "=&v"(r0), "=&v"(r1), "=&v"(r2), "=&v"(r3),
          "=&v"(r4), "=&v"(r5), "=&v"(r6), "=&v"(r7)
        : "v"(a0), "v"(a1), "v"(a2), "v"(a3), "v"(a4), "v"(a5),
          "v"(b0), "v"(b1), "v"(b2), "v"(b3), "v"(b4), "v"(b5), "v"(b6), "v"(b7)
        : "memory");
}

__device__ __forceinline__ void sc_load6(
    const uint4v* p0, const uint4v* p1, const uint4v* p2,
    const uint4v* p3, const uint4v* p4, const uint4v* p5,
    uint4v& r0, uint4v& r1, uint4v& r2, uint4v& r3, uint4v& r4, uint4v& r5)
{
    asm volatile(
        "global_load_dwordx4 %0, %6, off sc0 sc1\n\t"
        "global_load_dwordx4 %1, %7, off sc0 sc1\n\t"
        "global_load_dwordx4 %2, %8, off sc0 sc1\n\t"
        "global_load_dwordx4 %3, %9, off sc0 sc1\n\t"
        "global_load_dwordx4 %4, %10, off sc0 sc1\n\t"
        "global_load_dwordx4 %5, %11, off sc0 sc1\n\t"
        "s_waitcnt vmcnt(0)"
        : "=&v"(r0), "=&v"(r1), "=&v"(r2), "=&v"(r3), "=&v"(r4), "=&v"(r5)
        : "v"(p0), "v"(p1), "v"(p2), "v"(p3), "v"(p4), "v"(p5)
        : "memory");
}

__device__ __forceinline__ void sc_store2(uint4v* p0, uint4v v0, uint4v* p1, uint4v v1) {
    asm volatile(
        "global_store_dwordx4 %0, %2, off sc0 sc1\n\t"
        "global_store_dwordx4 %1, %3, off sc0 sc1\n\t"
        "s_waitcnt vmcnt(0)"
        :: "v"(p0), "v"(p1), "v"(v0), "v"(v1)
        : "memory");
}

// ---------------------------------------------------------------------------
__global__ void zero_ws_kernel(uint4v* __restrict__ p, int n16) {
    int i = blockIdx.x * 256 + threadIdx.x;
    uint4v z = {0u, 0u, 0u, 0u};
    if (i < n16) p[i] = z;
}

// Pack fp32 weight [K][N] into MFMA B-fragment order, fp16:
// dst[((nt*KT + kt)*64 + lane)*8 + j] = W[kt*32 + (lane>>4)*8 + j][nt*16 + (lane&15)]
__global__ void pack_w_kernel(const float* __restrict__ src, _Float16* __restrict__ dst,
                              int K, int N) {
    int idx = blockIdx.x * 256 + threadIdx.x;
    if (idx >= K * N) return;
    int j    = idx & 7;
    int lane = (idx >> 3) & 63;
    int rest = idx >> 9;
    int KT   = K >> 5;
    int kt   = rest % KT;
    int nt   = rest / KT;
    int k = kt*32 + (lane >> 4)*8 + j;
    int n = nt*16 + (lane & 15);
    dst[idx] = (_Float16)src[k * N + n];
}

// ---------------------------------------------------------------------------
__global__ __launch_bounds__(256, 1)
void rnn_main_kernel(const int*   __restrict__ tokens,
                     const float* __restrict__ emb,
                     const float* __restrict__ b0,
                     const float* __restrict__ b1,
                     char* ws)
{
    const int bid   = blockIdx.x;
    const int layer = bid >> 5;          // 0..2
    const int mg    = (bid >> 2) & 7;    // batch group (32 rows)
    const int ns    = bid & 3;           // N-strip (128 cols)
    const int tid   = threadIdx.x;
    const int wv    = tid >> 6;
    const int lane  = tid & 63;
    const int q     = lane >> 4;         // quad
    const int c16   = lane & 15;

    int* flags = (int*)ws;               // quad per (layer,mg), 128B apart
    int* qOwn  = flags + (layer*8 + mg)*32;
    int* qUp   = flags + ((layer > 0 ? layer-1 : layer)*8 + mg)*32;
    int* qDn   = flags + ((layer < 2 ? layer+1 : layer)*8 + mg)*32;

    _Float16* hbuf = (_Float16*)(ws + HBUF_OFF);
    const _Float16* pWh = (const _Float16*)(ws + (layer == 0 ? PWH0_OFF : PWH1_OFF));
    const _Float16* pWx = (const _Float16*)(ws + (layer == 0 ? PWX0_OFF : PWX1_OFF));
    const float* bias = (layer == 0) ? b0 : b1;

    const int c0  = ns*128 + wv*32;      // global col base of this wave
    const int nt0 = c0 >> 4;

    // LDS 72KB. Rows swizzled by 16B-chunk rotation (chunk' = (chunk+row)&63).
    __shared__ _Float16 Ah [32][512];    // h_l(t-1) A-tile
    __shared__ _Float16 Ain[32][512];    // input A-tile (x_t or h_{l-1}(t))
    __shared__ _Float16 Bounce[32][128]; // epilogue store-coalescing bounce

    // zero Ah: h(-1) = 0 (own strip; siblings come from zeroed ring at t=0)
    {
        uint4v z = {0u,0u,0u,0u};
#pragma unroll
        for (int i = 0; i < 8; ++i) ((uint4v*)Ah)[i*256 + tid] = z;
    }

    // ---- register-resident weights (B-fragments) ----
    half8 whf[16][2];
    half8 wxf[16][2];
#pragma unroll
    for (int kt = 0; kt < 16; ++kt)
#pragma unroll
        for (int n = 0; n < 2; ++n)
            whf[kt][n] = *(const half8*)&pWh[(((nt0 + n)*16 + kt)*64 + lane) * 8];
    if (layer == 0) {
#pragma unroll
        for (int kt = 0; kt < 4; ++kt)
#pragma unroll
            for (int n = 0; n < 2; ++n)
                wxf[kt][n] = *(const half8*)&pWx[(((nt0 + n)*4 + kt)*64 + lane) * 8];
    } else {
#pragma unroll
        for (int kt = 0; kt < 16; ++kt)
#pragma unroll
            for (int n = 0; n < 2; ++n)
                wxf[kt][n] = *(const half8*)&pWx[(((nt0 + n)*16 + kt)*64 + lane) * 8];
    }

    const float bv0 = bias[c0 + c16];
    const float bv1 = bias[c0 + 16 + c16];

    const int m0       = mg * 32;
    const int slotBase = (layer*8 + mg) * 4;

    // sibling strip ids (the 3 strips != ns, ascending)
    const int sA = (ns == 0) ? 1 : 0;
    const int sB = (ns <= 1) ? 2 : 1;
    const int sC = (ns <= 2) ? 3 : 2;

    for (int t = 0; t < SEQ; ++t) {
        // ---- poll (1 RT): own quad >= t, up quad >= t+1, down quad >= t-3 ----
        if (tid == 0) {
            for (;;) {
                int4v o, u, d;
                sc_ld_q3(qOwn, qUp, qDn, o, u, d);
                int mo = o[0] < o[1] ? o[0] : o[1];
                mo = mo < o[2] ? mo : o[2]; mo = mo < o[3] ? mo : o[3];
                int mu = u[0] < u[1] ? u[0] : u[1];
                mu = mu < u[2] ? mu : u[2]; mu = mu < u[3] ? mu : u[3];
                int md = d[0] < d[1] ? d[0] : d[1];
                md = md < d[2] ? md : d[2]; md = md < d[3] ? md : d[3];
                bool ok = (mo >= t);
                if (layer > 0)            ok = ok && (mu >= t + 1);
                if (layer < 2 && t >= 4)  ok = ok && (md >= t - 3);
                if (ok) break;
                __builtin_amdgcn_s_sleep(1);
            }
        }
        __syncthreads();   // (B) all deps satisfied

        // ---- chunk addressing ----
        const uint4v* tp = (const uint4v*)(hbuf + (slotBase + ((t + 3) & 3)) * 16384);
        const int j0 = 2*tid, j1 = j0 + 1;
        const int r0i = j0 >> 4, cl0 = j0 & 15;
        const int r1i = j1 >> 4, cl1 = j1 & 15;
        const int ccA0 = sA*16 + cl0, ccA1 = sA*16 + cl1;
        const int ccB0 = sB*16 + cl0, ccB1 = sB*16 + cl1;
        const int ccC0 = sC*16 + cl0, ccC1 = sC*16 + cl1;

        f32x4 acc00 = {0,0,0,0}, acc01 = {0,0,0,0}, acc10 = {0,0,0,0}, acc11 = {0,0,0,0};

        if (layer > 0) {
            const uint4v* sb = (const uint4v*)
                (hbuf + (((layer-1)*8 + mg)*4 + (t & 3)) * 16384);
            uint4v s0,s1,s2,s3,s4,s5, rr0,rr1,rr2,rr3,rr4,rr5,rr6,rr7;
            sc_load14(tp + r0i*64 + ccA0, tp + r1i*64 + ccA1,
                      tp + r0i*64 + ccB0, tp + r1i*64 + ccB1,
                      tp + r0i*64 + ccC0, tp + r1i*64 + ccC1,
                      sb +        tid, sb +  256 + tid, sb +  512 + tid, sb +  768 + tid,
                      sb + 1024 + tid, sb + 1280 + tid, sb + 1536 + tid, sb + 1792 + tid,
                      s0, s1, s2, s3, s4, s5,
                      rr0, rr1, rr2, rr3, rr4, rr5, rr6, rr7);
            *(uint4v*)&Ah[r0i][((ccA0 + r0i) & 63) * 8] = s0;
            *(uint4v*)&Ah[r1i][((ccA1 + r1i) & 63) * 8] = s1;
            *(uint4v*)&Ah[r0i][((ccB0 + r0i) & 63) * 8] = s2;
            *(uint4v*)&Ah[r1i][((ccB1 + r1i) & 63) * 8] = s3;
            *(uint4v*)&Ah[r0i][((ccC0 + r0i) & 63) * 8] = s4;
            *(uint4v*)&Ah[r1i][((ccC1 + r1i) & 63) * 8] = s5;
#pragma unroll
            for (int i = 0; i < 8; ++i) {
                uint4v v = (i==0)?rr0:(i==1)?rr1:(i==2)?rr2:(i==3)?rr3:
                           (i==4)?rr4:(i==5)?rr5:(i==6)?rr6:rr7;
                int ci = i*256 + tid;
                int r  = ci >> 6;
                int cc = ci & 63;
                *(uint4v*)&Ain[r][((cc + r) & 63) * 8] = v;
            }
            __syncthreads();   // (C) Ah + Ain ready

#pragma unroll
            for (int kt = 0; kt < 16; ++kt) {
                half8 a0 = *(const half8*)&Ah[c16]     [((kt*4 + q + c16)      & 63) * 8];
                half8 a1 = *(const half8*)&Ah[16 + c16][((kt*4 + q + 16 + c16) & 63) * 8];
                acc00 = __builtin_amdgcn_mfma_f32_16x16x32_f16(a0, whf[kt][0], acc00, 0, 0, 0);
                acc01 = __builtin_amdgcn_mfma_f32_16x16x32_f16(a0, whf[kt][1], acc01, 0, 0, 0);
                acc10 = __builtin_amdgcn_mfma_f32_16x16x32_f16(a1, whf[kt][0], acc10, 0, 0, 0);
                acc11 = __builtin_amdgcn_mfma_f32_16x16x32_f16(a1, whf[kt][1], acc11, 0, 0, 0);
            }
#pragma unroll
            for (int kt = 0; kt < 16; ++kt) {
                half8 a0 = *(const half8*)&Ain[c16]     [((kt*4 + q + c16)      & 63) * 8];
                half8 a1 = *(const half8*)&Ain[16 + c16][((kt*4 + q + 16 + c16) & 63) * 8];
                acc00 = __builtin_amdgcn_mfma_f32_16x16x32_f16(a0, wxf[kt][0], acc00, 0, 0, 0);
                acc01 = __builtin_amdgcn_mfma_f32_16x16x32_f16(a0, wxf[kt][1], acc01, 0, 0, 0);
                acc10 = __builtin_amdgcn_mfma_f32_16x16x32_f16(a1, wxf[kt][0], acc10, 0, 0, 0);
                acc11 = __builtin_amdgcn_mfma_f32_16x16x32_f16(a1, wxf[kt][1], acc11, 0, 0, 0);
            }
        } else {
            // layer 0: sibling Ah loads + embedding gather (plain cached loads)
            uint4v s0, s1, s2, s3, s4, s5;
            sc_load6(tp + r0i*64 + ccA0, tp + r1i*64 + ccA1,
                     tp + r0i*64 + ccB0, tp + r1i*64 + ccB1,
                     tp + r0i*64 + ccC0, tp + r1i*64 + ccC1,
                     s0, s1, s2, s3, s4, s5);
            *(uint4v*)&Ah[r0i][((ccA0 + r0i) & 63) * 8] = s0;
            *(uint4v*)&Ah[r1i][((ccA1 + r1i) & 63) * 8] = s1;
            *(uint4v*)&Ah[r0i][((ccB0 + r0i) & 63) * 8] = s2;
            *(uint4v*)&Ah[r1i][((ccB1 + r1i) & 63) * 8] = s3;
            *(uint4v*)&Ah[r0i][((ccC0 + r0i) & 63) * 8] = s4;
            *(uint4v*)&Ah[r1i][((ccC1 + r1i) & 63) * 8] = s5;
#pragma unroll
            for (int i = 0; i < 4; ++i) {
                int idx = i*256 + tid;           // 1024 float4 chunks (32 rows x 32)
                int r   = idx >> 5;
                int qq  = idx & 31;
                int tok = tokens[(m0 + r)*SEQ + t];
                float4 f = *((const float4*)(emb + (long)tok * EMBD) + qq);
                half4 h = { (_Float16)f.x, (_Float16)f.y, (_Float16)f.z, (_Float16)f.w };
                *(half4*)&Ain[r][((((qq >> 1) + r) & 63) * 8) + (qq & 1) * 4] = h;
            }
            __syncthreads();   // (C) Ah + Ain ready

#pragma unroll
            for (int kt = 0; kt < 16; ++kt) {
                half8 a0 = *(const half8*)&Ah[c16]     [((kt*4 + q + c16)      & 63) * 8];
                half8 a1 = *(const half8*)&Ah[16 + c16][((kt*4 + q + 16 + c16) & 63) * 8];
                acc00 = __builtin_amdgcn_mfma_f32_16x16x32_f16(a0, whf[kt][0], acc00, 0, 0, 0);
                acc01 = __builtin_amdgcn_mfma_f32_16x16x32_f16(a0, whf[kt][1], acc01, 0, 0, 0);
                acc10 = __builtin_amdgcn_mfma_f32_16x16x32_f16(a1, whf[kt][0], acc10, 0, 0, 0);
                acc11 = __builtin_amdgcn_mfma_f32_16x16x32_f16(a1, whf[kt][1], acc11, 0, 0, 0);
            }
#pragma unroll
            for (int kt = 0; kt < 4; ++kt) {
                half8 a0 = *(const half8*)&Ain[c16]     [((kt*4 + q + c16)      & 63) * 8];
                half8 a1 = *(const half8*)&Ain[16 + c16][((kt*4 + q + 16 + c16) & 63) * 8];
                acc00 = __builtin_amdgcn_mfma_f32_16x16x32_f16(a0, wxf[kt][0], acc00, 0, 0, 0);
                acc01 = __builtin_amdgcn_mfma_f32_16x16x32_f16(a0, wxf[kt][1], acc01, 0, 0, 0);
                acc10 = __builtin_amdgcn_mfma_f32_16x16x32_f16(a1, wxf[kt][0], acc10, 0, 0, 0);
                acc11 = __builtin_amdgcn_mfma_f32_16x16x32_f16(a1, wxf[kt][1], acc11, 0, 0, 0);
            }
        }

        // ---- tanh -> hv regs + Bounce (disjoint per-wave, no barrier needed) ----
        _Float16 hv[16];
#pragma unroll
        for (int r = 0; r < 4; ++r) {
            int row0 = q*4 + r, row1 = 16 + row0;
            float z, e; _Float16 v;
            z = acc00[r] + bv0; e = __expf(2.0f*z); v = (_Float16)(1.0f - 2.0f/(e + 1.0f));
            hv[r*4+0] = v; Bounce[row0][wv*32 + c16]      = v;
            z = acc01[r] + bv1; e = __expf(2.0f*z); v = (_Float16)(1.0f - 2.0f/(e + 1.0f));
            hv[r*4+1] = v; Bounce[row0][wv*32 + 16 + c16] = v;
            z = acc10[r] + bv0; e = __expf(2.0f*z); v = (_Float16)(1.0f - 2.0f/(e + 1.0f));
            hv[r*4+2] = v; Bounce[row1][wv*32 + c16]      = v;
            z = acc11[r] + bv1; e = __expf(2.0f*z); v = (_Float16)(1.0f - 2.0f/(e + 1.0f));
            hv[r*4+3] = v; Bounce[row1][wv*32 + 16 + c16] = v;
        }
        __syncthreads();   // (D) Ah/Ain reads done by all waves; Bounce complete

        // ---- own strip -> Ah(t); Bounce -> ring (coalesced sc, per-lane drain) ----
        {
            int g0 = c0 + c16, g1 = c0 + 16 + c16;
#pragma unroll
            for (int r = 0; r < 4; ++r) {
                int row0 = q*4 + r, row1 = 16 + row0;
                Ah[row0][(((g0 >> 3) + row0) & 63)*8 + (g0 & 7)] = hv[r*4+0];
                Ah[row0][(((g1 >> 3) + row0) & 63)*8 + (g1 & 7)] = hv[r*4+1];
                Ah[row1][(((g0 >> 3) + row1) & 63)*8 + (g0 & 7)] = hv[r*4+2];
                Ah[row1][(((g1 >> 3) + row1) & 63)*8 + (g1 & 7)] = hv[r*4+3];
            }
            _Float16* tc = hbuf + (slotBase + (t & 3)) * 16384;
            uint4v v0 = ((const uint4v*)Bounce)[j0];
            uint4v v1 = ((const uint4v*)Bounce)[j1];
            uint4v* d0 = (uint4v*)(tc + (j0 >> 4)*512 + ns*128) + (j0 & 15);
            uint4v* d1 = (uint4v*)(tc + (j1 >> 4)*512 + ns*128) + (j1 & 15);
            sc_store2(d0, v0, d1, v1);
        }
        __syncthreads();   // (E) all lanes drained; Ah(t) complete
        if (tid == 0) sc_st_int(qOwn + ns, t + 1);
    }
}

// ---------------------------------------------------------------------------
// logits = h2(T-1) @ fc_w + fc_b ; out = sigmoid(logits). One wave per row.
__global__ void fc_kernel(const char* __restrict__ ws,
                          const float* __restrict__ fc_w,
                          const float* __restrict__ fc_b,
                          float* __restrict__ out)
{
    int row  = blockIdx.x;
    int lane = threadIdx.x;          // 64
    int m = row >> 5, lr = row & 31;
    const _Float16* h2 = (const _Float16*)(ws + HBUF_OFF)
                         + (((2*8 + m)*4 + 3) * 16384)   // slot 511&3 = 3
                         + lr * UNIT;
    half8 hv = *(const half8*)&h2[lane * 8];
    const float* w = fc_w + lane * 8;
    float s = 0.0f;
#pragma unroll
    for (int j = 0; j < 8; ++j) s += (float)hv[j] * w[j];
#pragma unroll
    for (int off = 32; off > 0; off >>= 1) s += __shfl_down(s, off);
    if (lane == 0) {
        float logit = s + fc_b[0];
        out[row] = 1.0f / (1.0f + __expf(-logit));
    }
}

// ---------------------------------------------------------------------------
extern "C" void kernel_launch(void* const* d_in, const int* in_sizes, int n_in,
                              void* d_out, int out_size, void* d_ws, size_t ws_size,
                              hipStream_t stream)
{
    const int*   tokens = (const int*)  d_in[0];
    const float* emb    = (const float*)d_in[1];
    const float* Wx0    = (const float*)d_in[2];
    const float* Wh0    = (const float*)d_in[3];
    const float* b0     = (const float*)d_in[4];
    const float* Wx1    = (const float*)d_in[5];
    const float* Wh1    = (const float*)d_in[6];
    const float* b1     = (const float*)d_in[7];
    const float* fcw    = (const float*)d_in[8];
    const float* fcb    = (const float*)d_in[9];
    char*  ws  = (char*)d_ws;
    float* out = (float*)d_out;

    // 1) zero flags + h ring (t=0 reads ring slot 3 as h(-1)=0)
    int n16 = (FLAGS_BYTES + HBUF_BYTES) / 16;
    zero_ws_kernel<<<(n16 + 255)/256, 256, 0, stream>>>((uint4v*)ws, n16);

    // 2) pack weights fp32 -> fp16 B-fragment layout
    pack_w_kernel<<<(EMBD*UNIT + 255)/256, 256, 0, stream>>>(Wx0, (_Float16*)(ws + PWX0_OFF), EMBD, UNIT);
    pack_w_kernel<<<(UNIT*UNIT + 255)/256, 256, 0, stream>>>(Wh0, (_Float16*)(ws + PWH0_OFF), UNIT, UNIT);
    pack_w_kernel<<<(UNIT*UNIT + 255)/256, 256, 0, stream>>>(Wx1, (_Float16*)(ws + PWX1_OFF), UNIT, UNIT);
    pack_w_kernel<<<(UNIT*UNIT + 255)/256, 256, 0, stream>>>(Wh1, (_Float16*)(ws + PWH1_OFF), UNIT, UNIT);

    // 3) pipelined recurrence: 96 blocks = 3 layers x 8 batch-groups x 4 N-strips
    rnn_main_kernel<<<96, 256, 0, stream>>>(tokens, emb, b0, b1, ws);

    // 4) final FC + sigmoid
    fc_kernel<<<256, 64, 0, stream>>>((const char*)ws, fcw, fcb, out);
}